// Round 2
// baseline (6355.719 us; speedup 1.0000x reference)
//
#include <hip/hip_runtime.h>
#include <math.h>

#define N_IMG 128
#define EPS 1e-5f

// ---------- helpers ----------
__device__ __forceinline__ float gelu_f(float x) {
    return 0.5f * x * (1.0f + erff(x * 0.70710678118654752f));
}

__device__ __forceinline__ float wave_sum(float v) {
    #pragma unroll
    for (int m = 1; m < 64; m <<= 1) v += __shfl_xor(v, m);
    return v;
}

__device__ __forceinline__ void fma4(float4& acc, float s, const float4& v) {
    acc.x += s * v.x; acc.y += s * v.y; acc.z += s * v.z; acc.w += s * v.w;
}

__device__ __forceinline__ float dot4(const float4& a, const float4& b) {
    return a.x * b.x + a.y * b.y + a.z * b.z + a.w * b.w;
}

// ---------- positional-embedding table: pe[197][64] ----------
__global__ void k_posemb(float* __restrict__ pe) {
    int idx = blockIdx.x * 256 + threadIdx.x;
    if (idx >= 197 * 64) return;
    int i = idx >> 6, j = idx & 63;
    int jj = j & ~1;
    float inv = powf(10000.0f, (float)jj / 64.0f);
    float a = (float)i / inv;
    pe[idx] = (j & 1) ? cosf(a) : sinf(a);
}

// ---------- patch embed: tokens = patchify(img) @ lm_W + lm_b + pe[1+p] ----------
// M=25088 rows, K=1024, N=64. Tile 64 rows; A staged in LDS, W read from L2.
__global__ __launch_bounds__(256, 4) void k_patch(
    const float* __restrict__ img, const float* __restrict__ W,
    const float* __restrict__ bias, const float* __restrict__ pe,
    float* __restrict__ x)
{
    __shared__ float As[64 * 36];
    int tid = threadIdx.x;
    int tx = tid & 15, ty = tid >> 4;
    int m0 = blockIdx.x * 64;

    int ra = tid >> 2, ca = (tid & 3) * 8;
    int rowa = m0 + ra;
    int na = rowa / 196, pa = rowa - na * 196;
    const float* abase = img + (size_t)na * 200704 + (pa / 14) * (32 * 448) + (pa % 14) * 32 + ca;

    float4 acc[4];
    #pragma unroll
    for (int i = 0; i < 4; ++i) acc[i] = make_float4(0.f, 0.f, 0.f, 0.f);

    for (int kc = 0; kc < 32; ++kc) {
        float4 a0 = *(const float4*)(abase + kc * 448);
        float4 a1 = *(const float4*)(abase + kc * 448 + 4);
        __syncthreads();
        *(float4*)&As[ra * 36 + ca]     = a0;
        *(float4*)&As[ra * 36 + ca + 4] = a1;
        __syncthreads();
        #pragma unroll
        for (int k4 = 0; k4 < 8; ++k4) {
            float4 a[4], b[4];
            #pragma unroll
            for (int i = 0; i < 4; ++i) a[i] = *(float4*)&As[(ty + 16 * i) * 36 + k4 * 4];
            #pragma unroll
            for (int kk = 0; kk < 4; ++kk)
                b[kk] = *(const float4*)(W + (size_t)(kc * 32 + k4 * 4 + kk) * 64 + tx * 4);
            #pragma unroll
            for (int i = 0; i < 4; ++i) {
                fma4(acc[i], a[i].x, b[0]);
                fma4(acc[i], a[i].y, b[1]);
                fma4(acc[i], a[i].z, b[2]);
                fma4(acc[i], a[i].w, b[3]);
            }
        }
    }
    int col = tx * 4;
    float4 bb = *(const float4*)(bias + col);
    #pragma unroll
    for (int i = 0; i < 4; ++i) {
        int row = m0 + ty + 16 * i;
        int n = row / 196, p = row - n * 196;
        float4 pv = *(const float4*)(pe + (size_t)(1 + p) * 64 + col);
        float4 o;
        o.x = acc[i].x + bb.x + pv.x;
        o.y = acc[i].y + bb.y + pv.y;
        o.z = acc[i].z + bb.z + pv.z;
        o.w = acc[i].w + bb.w + pv.w;
        *(float4*)&x[((size_t)(n * 197 + 1 + p)) * 64 + col] = o;
    }
}

// ---------- class-token row ----------
__global__ void k_cls(const float* __restrict__ cls, const float* __restrict__ pe,
                      float* __restrict__ x) {
    int idx = blockIdx.x * 256 + threadIdx.x;
    if (idx >= 128 * 64) return;
    int n = idx >> 6, j = idx & 63;
    x[(size_t)n * 197 * 64 + j] = cls[j] + pe[j];
}

// ---------- LN1 + QKV projection ----------
__global__ __launch_bounds__(256) void k_ln_qkv(
    const float* __restrict__ x, const float* __restrict__ g, const float* __restrict__ bta,
    const float* __restrict__ Wq, const float* __restrict__ bq,
    const float* __restrict__ Wk, const float* __restrict__ bk,
    const float* __restrict__ Wv, const float* __restrict__ bv,
    float* __restrict__ q, float* __restrict__ k, float* __restrict__ v, int S)
{
    __shared__ float z[4][64];
    int tid = threadIdx.x, w = tid >> 6, l = tid & 63;
    int row = blockIdx.x * 4 + w;
    if (row >= N_IMG * S) return;
    float xv = x[(size_t)row * 64 + l];
    float m = wave_sum(xv) * (1.0f / 64.0f);
    float t = xv - m;
    float var = wave_sum(t * t) * (1.0f / 64.0f);
    float zv = t * rsqrtf(var + EPS) * g[l] + bta[l];
    z[w][l] = zv;
    int h = l >> 4, e = l & 15;
    const float* zh = &z[w][h * 16];
    const float* wq = Wq + h * 256 + e;
    const float* wk = Wk + h * 256 + e;
    const float* wv = Wv + h * 256 + e;
    float aq = bq[l], ak = bk[l], av = bv[l];
    #pragma unroll
    for (int d = 0; d < 16; ++d) {
        float zd = zh[d];
        aq += zd * wq[d * 16];
        ak += zd * wk[d * 16];
        av += zd * wv[d * 16];
    }
    int n = row / S, s = row - n * S;
    size_t o = ((size_t)((n * 4 + h) * S + s)) * 16 + e;
    q[o] = aq; k[o] = ak; v[o] = av;
}

// ---------- attention: lane-per-query, no-max softmax, 4x unrolled prefetch ----------
__global__ __launch_bounds__(256) void k_attn(
    const float* __restrict__ q, const float* __restrict__ k, const float* __restrict__ v,
    const float* __restrict__ x, float* __restrict__ hout, int S)
{
    int h = blockIdx.x & 3, n = blockIdx.x >> 2;
    int tid = threadIdx.x;
    int s = tid < S ? tid : S - 1;
    const float* qrow = q + ((size_t)((n * 4 + h) * S + s)) * 16;
    float4 q0 = *(const float4*)(qrow);
    float4 q1 = *(const float4*)(qrow + 4);
    float4 q2 = *(const float4*)(qrow + 8);
    float4 q3 = *(const float4*)(qrow + 12);
    q0.x *= 0.25f; q0.y *= 0.25f; q0.z *= 0.25f; q0.w *= 0.25f;
    q1.x *= 0.25f; q1.y *= 0.25f; q1.z *= 0.25f; q1.w *= 0.25f;
    q2.x *= 0.25f; q2.y *= 0.25f; q2.z *= 0.25f; q2.w *= 0.25f;
    q3.x *= 0.25f; q3.y *= 0.25f; q3.z *= 0.25f; q3.w *= 0.25f;
    const float* kp = k + (size_t)(n * 4 + h) * S * 16;
    const float* vp = v + (size_t)(n * 4 + h) * S * 16;
    float l = 0.0f;
    float4 o0 = make_float4(0.f, 0.f, 0.f, 0.f), o1 = o0, o2 = o0, o3 = o0;

    int j = 0;
    for (; j + 4 <= S; j += 4) {
        float4 ka[4][4], va[4][4];
        #pragma unroll
        for (int u = 0; u < 4; ++u) {
            #pragma unroll
            for (int c = 0; c < 4; ++c) {
                ka[u][c] = *(const float4*)(kp + (size_t)(j + u) * 16 + c * 4);
                va[u][c] = *(const float4*)(vp + (size_t)(j + u) * 16 + c * 4);
            }
        }
        #pragma unroll
        for (int u = 0; u < 4; ++u) {
            float sc = dot4(q0, ka[u][0]) + dot4(q1, ka[u][1]) +
                       dot4(q2, ka[u][2]) + dot4(q3, ka[u][3]);
            float p = __expf(sc);
            l += p;
            fma4(o0, p, va[u][0]); fma4(o1, p, va[u][1]);
            fma4(o2, p, va[u][2]); fma4(o3, p, va[u][3]);
        }
    }
    for (; j < S; ++j) {
        float4 ka[4], va[4];
        #pragma unroll
        for (int c = 0; c < 4; ++c) {
            ka[c] = *(const float4*)(kp + (size_t)j * 16 + c * 4);
            va[c] = *(const float4*)(vp + (size_t)j * 16 + c * 4);
        }
        float sc = dot4(q0, ka[0]) + dot4(q1, ka[1]) + dot4(q2, ka[2]) + dot4(q3, ka[3]);
        float p = __expf(sc);
        l += p;
        fma4(o0, p, va[0]); fma4(o1, p, va[1]); fma4(o2, p, va[2]); fma4(o3, p, va[3]);
    }
    float rl = 1.0f / l;
    if (tid < S) {
        size_t base = ((size_t)n * S + tid) * 64 + h * 16;
        float4 ov[4] = {o0, o1, o2, o3};
        #pragma unroll
        for (int e4 = 0; e4 < 4; ++e4) {
            float4 xv = *(const float4*)(x + base + e4 * 4);
            float4 w;
            w.x = xv.x + ov[e4].x * rl;
            w.y = xv.y + ov[e4].y * rl;
            w.z = xv.z + ov[e4].z * rl;
            w.w = xv.w + ov[e4].w * rl;
            *(float4*)(hout + base + e4 * 4) = w;
        }
    }
}

// ---------- LN2 + GEMM [rows,64]@[64,256] + bias + GELU -> mid ----------
// grid (2, rows/64): LN once per block, two 64-col quarters per block, W1 from L2.
__global__ __launch_bounds__(256, 4) void k_mlp1(
    const float* __restrict__ hbuf, const float* __restrict__ g, const float* __restrict__ bta,
    const float* __restrict__ W1, const float* __restrict__ b1,
    float* __restrict__ mid)
{
    __shared__ float As[64 * 68];
    int tid = threadIdx.x;
    int tx = tid & 15, ty = tid >> 4;
    int m0 = blockIdx.y * 64;
    int nh = blockIdx.x;   // 0..1
    int r = tid >> 2, cpart = (tid & 3) * 16;
    {
        const float* hp = hbuf + ((size_t)(m0 + r)) * 64 + cpart;
        float4 hv[4];
        #pragma unroll
        for (int i = 0; i < 4; ++i) hv[i] = *(const float4*)(hp + i * 4);
        float ps = 0.f;
        #pragma unroll
        for (int i = 0; i < 4; ++i) ps += hv[i].x + hv[i].y + hv[i].z + hv[i].w;
        ps += __shfl_xor(ps, 1); ps += __shfl_xor(ps, 2);
        float mean = ps * (1.0f / 64.0f);
        float vs = 0.f;
        #pragma unroll
        for (int i = 0; i < 4; ++i) {
            float dx = hv[i].x - mean, dy = hv[i].y - mean, dz = hv[i].z - mean, dw = hv[i].w - mean;
            vs += dx * dx + dy * dy + dz * dz + dw * dw;
        }
        vs += __shfl_xor(vs, 1); vs += __shfl_xor(vs, 2);
        float rstd = rsqrtf(vs * (1.0f / 64.0f) + EPS);
        #pragma unroll
        for (int i = 0; i < 4; ++i) {
            float4 gv = *(const float4*)(g + cpart + i * 4);
            float4 bv = *(const float4*)(bta + cpart + i * 4);
            float4 zv;
            zv.x = (hv[i].x - mean) * rstd * gv.x + bv.x;
            zv.y = (hv[i].y - mean) * rstd * gv.y + bv.y;
            zv.z = (hv[i].z - mean) * rstd * gv.z + bv.z;
            zv.w = (hv[i].w - mean) * rstd * gv.w + bv.w;
            *(float4*)&As[r * 68 + cpart + i * 4] = zv;
        }
    }
    __syncthreads();
    #pragma unroll
    for (int qq = 0; qq < 2; ++qq) {
        int colbase = nh * 128 + qq * 64;
        float4 acc[4];
        #pragma unroll
        for (int i = 0; i < 4; ++i) acc[i] = make_float4(0.f, 0.f, 0.f, 0.f);
        #pragma unroll
        for (int k4 = 0; k4 < 16; ++k4) {
            float4 a[4], b[4];
            #pragma unroll
            for (int i = 0; i < 4; ++i) a[i] = *(float4*)&As[(ty + 16 * i) * 68 + k4 * 4];
            #pragma unroll
            for (int kk = 0; kk < 4; ++kk)
                b[kk] = *(const float4*)(W1 + (size_t)(k4 * 4 + kk) * 256 + colbase + tx * 4);
            #pragma unroll
            for (int i = 0; i < 4; ++i) {
                fma4(acc[i], a[i].x, b[0]);
                fma4(acc[i], a[i].y, b[1]);
                fma4(acc[i], a[i].z, b[2]);
                fma4(acc[i], a[i].w, b[3]);
            }
        }
        int col = colbase + tx * 4;
        float4 b1v = *(const float4*)(b1 + col);
        #pragma unroll
        for (int i = 0; i < 4; ++i) {
            int row = m0 + ty + 16 * i;
            float4 ov;
            ov.x = gelu_f(acc[i].x + b1v.x);
            ov.y = gelu_f(acc[i].y + b1v.y);
            ov.z = gelu_f(acc[i].z + b1v.z);
            ov.w = gelu_f(acc[i].w + b1v.w);
            *(float4*)&mid[(size_t)row * 256 + col] = ov;
        }
    }
}

// ---------- GEMM [rows,256]@[256,64] + bias + residual -> out ----------
__global__ __launch_bounds__(256, 4) void k_mlp2(
    const float* __restrict__ mid, const float* __restrict__ W2, const float* __restrict__ b2,
    const float* __restrict__ hbuf, float* __restrict__ out)
{
    __shared__ float As[64 * 68];
    int tid = threadIdx.x;
    int tx = tid & 15, ty = tid >> 4;
    int m0 = blockIdx.x * 64;
    int r = tid >> 2, cpart = (tid & 3) * 16;
    float4 acc[4];
    #pragma unroll
    for (int i = 0; i < 4; ++i) acc[i] = make_float4(0.f, 0.f, 0.f, 0.f);
    for (int kc = 0; kc < 4; ++kc) {
        const float* mp = mid + ((size_t)(m0 + r)) * 256 + kc * 64 + cpart;
        float4 av[4];
        #pragma unroll
        for (int i = 0; i < 4; ++i) av[i] = *(const float4*)(mp + i * 4);
        __syncthreads();
        #pragma unroll
        for (int i = 0; i < 4; ++i)
            *(float4*)&As[r * 68 + cpart + i * 4] = av[i];
        __syncthreads();
        #pragma unroll
        for (int k4 = 0; k4 < 16; ++k4) {
            float4 a[4], b[4];
            #pragma unroll
            for (int i = 0; i < 4; ++i) a[i] = *(float4*)&As[(ty + 16 * i) * 68 + k4 * 4];
            #pragma unroll
            for (int kk = 0; kk < 4; ++kk)
                b[kk] = *(const float4*)(W2 + (size_t)(kc * 64 + k4 * 4 + kk) * 64 + tx * 4);
            #pragma unroll
            for (int i = 0; i < 4; ++i) {
                fma4(acc[i], a[i].x, b[0]);
                fma4(acc[i], a[i].y, b[1]);
                fma4(acc[i], a[i].z, b[2]);
                fma4(acc[i], a[i].w, b[3]);
            }
        }
    }
    int col = tx * 4;
    float4 b2v = *(const float4*)(b2 + col);
    #pragma unroll
    for (int i = 0; i < 4; ++i) {
        int row = m0 + ty + 16 * i;
        float4 hv = *(const float4*)(hbuf + (size_t)row * 64 + col);
        float4 ov;
        ov.x = acc[i].x + b2v.x + hv.x;
        ov.y = acc[i].y + b2v.y + hv.y;
        ov.z = acc[i].z + b2v.z + hv.z;
        ov.w = acc[i].w + b2v.w + hv.w;
        *(float4*)&out[(size_t)row * 64 + col] = ov;
    }
}

// ---------- bottleneck ----------
__global__ __launch_bounds__(256) void k_bneck(
    const float* __restrict__ xenc, const float* __restrict__ m1W, const float* __restrict__ m1b,
    const float* __restrict__ m4W, const float* __restrict__ m4b,
    float* __restrict__ lat_out, float* __restrict__ xdec)
{
    int tid = threadIdx.x, w = tid >> 6, l = tid & 63;
    int row = blockIdx.x * 4 + w;
    if (row >= 128 * 196) return;
    int n = row / 196, p = row - n * 196;
    float xv = xenc[((size_t)(n * 197 + 1 + p)) * 64 + l];
    float sum = wave_sum(xv * m1W[l]);
    float lat = gelu_f(sum + m1b[0]);
    if (l == 0) lat_out[row] = lat;
    float ov = gelu_f(lat * m4W[l] + m4b[l]);
    xdec[(size_t)row * 64 + l] = ov;
}

// ---------- final: img = depatchify((x + pe196) @ lm2_W + lm2_b) ----------
// grid rows/64; A staged once; loop 16 column tiles; W from L2.
__global__ __launch_bounds__(256, 4) void k_final(
    const float* __restrict__ xdec, const float* __restrict__ pe,
    const float* __restrict__ W, const float* __restrict__ bias,
    float* __restrict__ img_out)
{
    __shared__ float As[64 * 68];
    int tid = threadIdx.x;
    int tx = tid & 15, ty = tid >> 4;
    int m0 = blockIdx.x * 64;
    int r = tid >> 2, cpart = (tid & 3) * 16;
    {
        int row = m0 + r;
        int n = row / 196, p = row - n * 196;
        const float* xp = xdec + (size_t)row * 64 + cpart;
        const float* pp = pe + (size_t)p * 64 + cpart;
        #pragma unroll
        for (int i = 0; i < 4; ++i) {
            float4 xv = *(const float4*)(xp + i * 4);
            float4 pv = *(const float4*)(pp + i * 4);
            float4 zv;
            zv.x = xv.x + pv.x; zv.y = xv.y + pv.y; zv.z = xv.z + pv.z; zv.w = xv.w + pv.w;
            *(float4*)&As[r * 68 + cpart + i * 4] = zv;
        }
    }
    __syncthreads();
    for (int nb = 0; nb < 16; ++nb) {
        float4 acc[4];
        #pragma unroll
        for (int i = 0; i < 4; ++i) acc[i] = make_float4(0.f, 0.f, 0.f, 0.f);
        #pragma unroll
        for (int k4 = 0; k4 < 16; ++k4) {
            float4 a[4], b[4];
            #pragma unroll
            for (int i = 0; i < 4; ++i) a[i] = *(float4*)&As[(ty + 16 * i) * 68 + k4 * 4];
            #pragma unroll
            for (int kk = 0; kk < 4; ++kk)
                b[kk] = *(const float4*)(W + (size_t)(k4 * 4 + kk) * 1024 + nb * 64 + tx * 4);
            #pragma unroll
            for (int i = 0; i < 4; ++i) {
                fma4(acc[i], a[i].x, b[0]);
                fma4(acc[i], a[i].y, b[1]);
                fma4(acc[i], a[i].z, b[2]);
                fma4(acc[i], a[i].w, b[3]);
            }
        }
        int colj = nb * 64 + tx * 4;
        float4 bv = *(const float4*)(bias + colj);
        int rr = colj >> 5, cc = colj & 31;
        #pragma unroll
        for (int i = 0; i < 4; ++i) {
            int row = m0 + ty + 16 * i;
            int n = row / 196, p = row - n * 196;
            int pi = p / 14, pj = p - pi * 14;
            size_t off = (size_t)n * 200704 + (size_t)(pi * 32 + rr) * 448 + pj * 32 + cc;
            float4 ov;
            ov.x = acc[i].x + bv.x;
            ov.y = acc[i].y + bv.y;
            ov.z = acc[i].z + bv.z;
            ov.w = acc[i].w + bv.w;
            *(float4*)&img_out[off] = ov;
        }
    }
}

// ---------- host launch ----------
extern "C" void kernel_launch(void* const* d_in, const int* in_sizes, int n_in,
                              void* d_out, int out_size, void* d_ws, size_t ws_size,
                              hipStream_t stream) {
    const float* images = (const float*)d_in[0];
    const float* cls    = (const float*)d_in[1];
    const float* lm_W   = (const float*)d_in[2];
    const float* lm_b   = (const float*)d_in[3];
    const float* lm2_W  = (const float*)d_in[4];
    const float* lm2_b  = (const float*)d_in[5];
    const float* m1W    = (const float*)d_in[6];
    const float* m1b    = (const float*)d_in[7];
    const float* m4W    = (const float*)d_in[8];
    const float* m4b    = (const float*)d_in[9];

    float* pe   = (float*)d_ws;
    float* xb   = pe + 12608;          // 128*197*64
    float* hb   = xb + 1614848;
    float* qb   = hb + 1614848;
    float* kb   = qb + 1614848;
    float* vb   = kb + 1614848;
    float* midb = vb + 1614848;        // 25216*256

    float* lat_out = (float*)d_out;            // 128*196 floats
    float* img_out = (float*)d_out + 25088;    // 128*448*448 floats

    hipLaunchKernelGGL(k_posemb, dim3(50), dim3(256), 0, stream, pe);
    hipLaunchKernelGGL(k_patch, dim3(392), dim3(256), 0, stream, images, lm_W, lm_b, pe, xb);
    hipLaunchKernelGGL(k_cls, dim3(32), dim3(256), 0, stream, cls, pe, xb);

    float* cur_x = xb;
    float* cur_h = hb;
    for (int grp = 0; grp < 2; ++grp) {
        int base = 10 + grp * 14;
        const float* ln1_g = (const float*)d_in[base + 0];
        const float* ln1_b = (const float*)d_in[base + 1];
        const float* ln2_g = (const float*)d_in[base + 2];
        const float* ln2_b = (const float*)d_in[base + 3];
        const float* Wq = (const float*)d_in[base + 4];
        const float* Wk = (const float*)d_in[base + 5];
        const float* Wv = (const float*)d_in[base + 6];
        const float* bq = (const float*)d_in[base + 7];
        const float* bk = (const float*)d_in[base + 8];
        const float* bv = (const float*)d_in[base + 9];
        const float* W1 = (const float*)d_in[base + 10];
        const float* b1 = (const float*)d_in[base + 11];
        const float* W2 = (const float*)d_in[base + 12];
        const float* b2 = (const float*)d_in[base + 13];
        int S = (grp == 0) ? 197 : 196;
        int rows = 128 * S;
        for (int i = 0; i < 2; ++i) {
            hipLaunchKernelGGL(k_ln_qkv, dim3(rows / 4), dim3(256), 0, stream,
                cur_x, ln1_g + i * 64, ln1_b + i * 64,
                Wq + i * 1024, bq + i * 64, Wk + i * 1024, bk + i * 64,
                Wv + i * 1024, bv + i * 64, qb, kb, vb, S);
            hipLaunchKernelGGL(k_attn, dim3(512), dim3(256), 0, stream,
                qb, kb, vb, cur_x, cur_h, S);
            hipLaunchKernelGGL(k_mlp1, dim3(2, rows / 64), dim3(256), 0, stream,
                cur_h, ln2_g + i * 64, ln2_b + i * 64, W1 + i * 16384, b1 + i * 256, midb);
            hipLaunchKernelGGL(k_mlp2, dim3(rows / 64), dim3(256), 0, stream,
                midb, W2 + i * 16384, b2 + i * 64, cur_h, cur_x);
        }
        if (grp == 0) {
            hipLaunchKernelGGL(k_bneck, dim3(6272), dim3(256), 0, stream,
                cur_x, m1W, m1b, m4W, m4b, lat_out, hb);
            cur_x = hb;
            cur_h = xb;
        }
    }
    hipLaunchKernelGGL(k_final, dim3(392), dim3(256), 0, stream, cur_x, pe, lm2_W, lm2_b, img_out);
}

// Round 3
// 918.621 us; speedup vs baseline: 6.9188x; 6.9188x over previous
//
#include <hip/hip_runtime.h>
#include <math.h>

#define N_IMG 128
#define EPS 1e-5f

// ---------- helpers ----------
__device__ __forceinline__ float gelu_f(float x) {
    return 0.5f * x * (1.0f + erff(x * 0.70710678118654752f));
}

__device__ __forceinline__ float wave_sum(float v) {
    #pragma unroll
    for (int m = 1; m < 64; m <<= 1) v += __shfl_xor(v, m);
    return v;
}

__device__ __forceinline__ void fma4(float4& acc, float s, const float4& v) {
    acc.x += s * v.x; acc.y += s * v.y; acc.z += s * v.z; acc.w += s * v.w;
}

__device__ __forceinline__ float dot4(const float4& a, const float4& b) {
    return a.x * b.x + a.y * b.y + a.z * b.z + a.w * b.w;
}

// ---------- positional-embedding table: pe[197][64] ----------
__global__ void k_posemb(float* __restrict__ pe) {
    int idx = blockIdx.x * 256 + threadIdx.x;
    if (idx >= 197 * 64) return;
    int i = idx >> 6, j = idx & 63;
    int jj = j & ~1;
    float inv = powf(10000.0f, (float)jj / 64.0f);
    float a = (float)i / inv;
    pe[idx] = (j & 1) ? cosf(a) : sinf(a);
}

// ---------- patch embed: tokens = patchify(img) @ lm_W + lm_b + pe[1+p] ----------
__global__ __launch_bounds__(256, 2) void k_patch(
    const float* __restrict__ img, const float* __restrict__ W,
    const float* __restrict__ bias, const float* __restrict__ pe,
    float* __restrict__ x)
{
    __shared__ float As[64 * 36];
    __shared__ float Bs[32 * 64];
    int tid = threadIdx.x;
    int tx = tid & 15, ty = tid >> 4;
    int m0 = blockIdx.x * 64;

    int ra = tid >> 2, ca = (tid & 3) * 8;
    int rowa = m0 + ra;
    int na = rowa / 196, pa = rowa - na * 196;
    const float* abase = img + (size_t)na * 200704 + (pa / 14) * (32 * 448) + (pa % 14) * 32 + ca;

    int kr = tid >> 3, cb = (tid & 7) * 8;

    float4 acc[4];
    #pragma unroll
    for (int i = 0; i < 4; ++i) acc[i] = make_float4(0.f, 0.f, 0.f, 0.f);

    for (int kc = 0; kc < 32; ++kc) {
        float4 a0 = *(const float4*)(abase + kc * 448);
        float4 a1 = *(const float4*)(abase + kc * 448 + 4);
        const float* wp = W + (size_t)(kc * 32 + kr) * 64 + cb;
        float4 b0 = *(const float4*)(wp);
        float4 b1 = *(const float4*)(wp + 4);
        __syncthreads();
        *(float4*)&As[ra * 36 + ca]     = a0;
        *(float4*)&As[ra * 36 + ca + 4] = a1;
        *(float4*)&Bs[kr * 64 + cb]     = b0;
        *(float4*)&Bs[kr * 64 + cb + 4] = b1;
        __syncthreads();
        #pragma unroll 4
        for (int k4 = 0; k4 < 8; ++k4) {
            float4 a[4], b[4];
            #pragma unroll
            for (int i = 0; i < 4; ++i) a[i] = *(float4*)&As[(ty + 16 * i) * 36 + k4 * 4];
            #pragma unroll
            for (int kk = 0; kk < 4; ++kk) b[kk] = *(float4*)&Bs[(k4 * 4 + kk) * 64 + tx * 4];
            #pragma unroll
            for (int i = 0; i < 4; ++i) {
                fma4(acc[i], a[i].x, b[0]);
                fma4(acc[i], a[i].y, b[1]);
                fma4(acc[i], a[i].z, b[2]);
                fma4(acc[i], a[i].w, b[3]);
            }
        }
    }
    int col = tx * 4;
    float4 bb = *(const float4*)(bias + col);
    #pragma unroll
    for (int i = 0; i < 4; ++i) {
        int row = m0 + ty + 16 * i;
        int n = row / 196, p = row - n * 196;
        float4 pv = *(const float4*)(pe + (size_t)(1 + p) * 64 + col);
        float4 o;
        o.x = acc[i].x + bb.x + pv.x;
        o.y = acc[i].y + bb.y + pv.y;
        o.z = acc[i].z + bb.z + pv.z;
        o.w = acc[i].w + bb.w + pv.w;
        *(float4*)&x[((size_t)(n * 197 + 1 + p)) * 64 + col] = o;
    }
}

// ---------- class-token row ----------
__global__ void k_cls(const float* __restrict__ cls, const float* __restrict__ pe,
                      float* __restrict__ x) {
    int idx = blockIdx.x * 256 + threadIdx.x;
    if (idx >= 128 * 64) return;
    int n = idx >> 6, j = idx & 63;
    x[(size_t)n * 197 * 64 + j] = cls[j] + pe[j];
}

// ---------- LN1 + QKV projection ----------
__global__ __launch_bounds__(256, 2) void k_ln_qkv(
    const float* __restrict__ x, const float* __restrict__ g, const float* __restrict__ bta,
    const float* __restrict__ Wq, const float* __restrict__ bq,
    const float* __restrict__ Wk, const float* __restrict__ bk,
    const float* __restrict__ Wv, const float* __restrict__ bv,
    float* __restrict__ q, float* __restrict__ k, float* __restrict__ v, int S)
{
    __shared__ float z[4][64];
    int tid = threadIdx.x, w = tid >> 6, l = tid & 63;
    int row = blockIdx.x * 4 + w;
    if (row >= N_IMG * S) return;
    float xv = x[(size_t)row * 64 + l];
    float m = wave_sum(xv) * (1.0f / 64.0f);
    float t = xv - m;
    float var = wave_sum(t * t) * (1.0f / 64.0f);
    float zv = t * rsqrtf(var + EPS) * g[l] + bta[l];
    z[w][l] = zv;
    int h = l >> 4, e = l & 15;
    const float* zh = &z[w][h * 16];
    const float* wq = Wq + h * 256 + e;
    const float* wk = Wk + h * 256 + e;
    const float* wv = Wv + h * 256 + e;
    float aq = bq[l], ak = bk[l], av = bv[l];
    #pragma unroll
    for (int d = 0; d < 16; ++d) {
        float zd = zh[d];
        aq += zd * wq[d * 16];
        ak += zd * wk[d * 16];
        av += zd * wv[d * 16];
    }
    int n = row / S, s = row - n * S;
    size_t o = ((size_t)((n * 4 + h) * S + s)) * 16 + e;
    q[o] = aq; k[o] = ak; v[o] = av;
}

// ---------- attention: lane-per-query, explicit 2-deep pipelined K/V prefetch ----------
struct KV { float4 k[2][4]; float4 v[2][4]; };

__device__ __forceinline__ void ld_pair(KV& b, const float* kp, const float* vp, int j) {
    #pragma unroll
    for (int u = 0; u < 2; ++u) {
        #pragma unroll
        for (int c = 0; c < 4; ++c) {
            b.k[u][c] = *(const float4*)(kp + (size_t)(j + u) * 16 + c * 4);
            b.v[u][c] = *(const float4*)(vp + (size_t)(j + u) * 16 + c * 4);
        }
    }
}

__device__ __forceinline__ void comp_one(const KV& b, int u, const float4* qv,
                                         float& l, float4* o) {
    float sc = dot4(qv[0], b.k[u][0]) + dot4(qv[1], b.k[u][1]) +
               dot4(qv[2], b.k[u][2]) + dot4(qv[3], b.k[u][3]);
    float p = __expf(sc);
    l += p;
    fma4(o[0], p, b.v[u][0]); fma4(o[1], p, b.v[u][1]);
    fma4(o[2], p, b.v[u][2]); fma4(o[3], p, b.v[u][3]);
}

__global__ __launch_bounds__(256, 2) void k_attn(
    const float* __restrict__ q, const float* __restrict__ k, const float* __restrict__ v,
    const float* __restrict__ x, float* __restrict__ hout, int S)
{
    int h = blockIdx.x & 3, n = blockIdx.x >> 2;
    int tid = threadIdx.x;
    int s = tid < S ? tid : S - 1;
    const float* qrow = q + ((size_t)((n * 4 + h) * S + s)) * 16;
    float4 qv[4];
    #pragma unroll
    for (int c = 0; c < 4; ++c) {
        float4 t = *(const float4*)(qrow + c * 4);
        t.x *= 0.25f; t.y *= 0.25f; t.z *= 0.25f; t.w *= 0.25f;
        qv[c] = t;
    }
    const float* kp = k + (size_t)(n * 4 + h) * S * 16;
    const float* vp = v + (size_t)(n * 4 + h) * S * 16;
    float l = 0.0f;
    float4 o[4];
    #pragma unroll
    for (int c = 0; c < 4; ++c) o[c] = make_float4(0.f, 0.f, 0.f, 0.f);

    KV A, B;
    ld_pair(A, kp, vp, 0);
    int j = 0;
    for (; j + 4 <= S; j += 4) {
        ld_pair(B, kp, vp, j + 2);        // prefetch pair j+2 (overread @ tail is in-ws, unused)
        comp_one(A, 0, qv, l, o);
        comp_one(A, 1, qv, l, o);
        ld_pair(A, kp, vp, j + 4);        // prefetch pair j+4
        comp_one(B, 0, qv, l, o);
        comp_one(B, 1, qv, l, o);
    }
    int rem = S - j;                       // 0..3; A holds rows j, j+1
    if (rem > 0) comp_one(A, 0, qv, l, o);
    if (rem > 1) comp_one(A, 1, qv, l, o);
    if (rem > 2) {
        ld_pair(B, kp, vp, j + 2);
        comp_one(B, 0, qv, l, o);
    }

    float rl = 1.0f / l;
    if (tid < S) {
        size_t base = ((size_t)n * S + tid) * 64 + h * 16;
        #pragma unroll
        for (int e4 = 0; e4 < 4; ++e4) {
            float4 xv = *(const float4*)(x + base + e4 * 4);
            float4 w;
            w.x = xv.x + o[e4].x * rl;
            w.y = xv.y + o[e4].y * rl;
            w.z = xv.z + o[e4].z * rl;
            w.w = xv.w + o[e4].w * rl;
            *(float4*)(hout + base + e4 * 4) = w;
        }
    }
}

// ---------- LN2 + GEMM [rows,64]@[64,256] + bias + GELU -> mid ----------
// grid rows/64: LN+A-stage once, loop 4 column tiles with LDS-staged B.
__global__ __launch_bounds__(256, 2) void k_mlp1(
    const float* __restrict__ hbuf, const float* __restrict__ g, const float* __restrict__ bta,
    const float* __restrict__ W1, const float* __restrict__ b1,
    float* __restrict__ mid)
{
    __shared__ float As[64 * 68];
    __shared__ float Bs[64 * 64];
    int tid = threadIdx.x;
    int tx = tid & 15, ty = tid >> 4;
    int m0 = blockIdx.x * 64;
    int r = tid >> 2, cpart = (tid & 3) * 16;
    {
        const float* hp = hbuf + ((size_t)(m0 + r)) * 64 + cpart;
        float4 hv[4];
        #pragma unroll
        for (int i = 0; i < 4; ++i) hv[i] = *(const float4*)(hp + i * 4);
        float ps = 0.f;
        #pragma unroll
        for (int i = 0; i < 4; ++i) ps += hv[i].x + hv[i].y + hv[i].z + hv[i].w;
        ps += __shfl_xor(ps, 1); ps += __shfl_xor(ps, 2);
        float mean = ps * (1.0f / 64.0f);
        float vs = 0.f;
        #pragma unroll
        for (int i = 0; i < 4; ++i) {
            float dx = hv[i].x - mean, dy = hv[i].y - mean, dz = hv[i].z - mean, dw = hv[i].w - mean;
            vs += dx * dx + dy * dy + dz * dz + dw * dw;
        }
        vs += __shfl_xor(vs, 1); vs += __shfl_xor(vs, 2);
        float rstd = rsqrtf(vs * (1.0f / 64.0f) + EPS);
        #pragma unroll
        for (int i = 0; i < 4; ++i) {
            float4 gv = *(const float4*)(g + cpart + i * 4);
            float4 bv = *(const float4*)(bta + cpart + i * 4);
            float4 zv;
            zv.x = (hv[i].x - mean) * rstd * gv.x + bv.x;
            zv.y = (hv[i].y - mean) * rstd * gv.y + bv.y;
            zv.z = (hv[i].z - mean) * rstd * gv.z + bv.z;
            zv.w = (hv[i].w - mean) * rstd * gv.w + bv.w;
            *(float4*)&As[r * 68 + cpart + i * 4] = zv;
        }
    }
    for (int nc = 0; nc < 4; ++nc) {
        const float* wp = W1 + (size_t)r * 256 + nc * 64 + cpart;
        float4 wv4[4];
        #pragma unroll
        for (int i = 0; i < 4; ++i) wv4[i] = *(const float4*)(wp + i * 4);
        __syncthreads();
        #pragma unroll
        for (int i = 0; i < 4; ++i)
            *(float4*)&Bs[r * 64 + cpart + i * 4] = wv4[i];
        __syncthreads();
        float4 acc[4];
        #pragma unroll
        for (int i = 0; i < 4; ++i) acc[i] = make_float4(0.f, 0.f, 0.f, 0.f);
        #pragma unroll 4
        for (int k4 = 0; k4 < 16; ++k4) {
            float4 a[4], b[4];
            #pragma unroll
            for (int i = 0; i < 4; ++i) a[i] = *(float4*)&As[(ty + 16 * i) * 68 + k4 * 4];
            #pragma unroll
            for (int kk = 0; kk < 4; ++kk) b[kk] = *(float4*)&Bs[(k4 * 4 + kk) * 64 + tx * 4];
            #pragma unroll
            for (int i = 0; i < 4; ++i) {
                fma4(acc[i], a[i].x, b[0]);
                fma4(acc[i], a[i].y, b[1]);
                fma4(acc[i], a[i].z, b[2]);
                fma4(acc[i], a[i].w, b[3]);
            }
        }
        int col = nc * 64 + tx * 4;
        float4 b1v = *(const float4*)(b1 + col);
        #pragma unroll
        for (int i = 0; i < 4; ++i) {
            int row = m0 + ty + 16 * i;
            float4 ov;
            ov.x = gelu_f(acc[i].x + b1v.x);
            ov.y = gelu_f(acc[i].y + b1v.y);
            ov.z = gelu_f(acc[i].z + b1v.z);
            ov.w = gelu_f(acc[i].w + b1v.w);
            *(float4*)&mid[(size_t)row * 256 + col] = ov;
        }
    }
}

// ---------- GEMM [rows,256]@[256,64] + bias + residual -> out ----------
__global__ __launch_bounds__(256, 2) void k_mlp2(
    const float* __restrict__ mid, const float* __restrict__ W2, const float* __restrict__ b2,
    const float* __restrict__ hbuf, float* __restrict__ out)
{
    __shared__ float As[64 * 68];
    __shared__ float Bs[64 * 64];
    int tid = threadIdx.x;
    int tx = tid & 15, ty = tid >> 4;
    int m0 = blockIdx.x * 64;
    int r = tid >> 2, cpart = (tid & 3) * 16;
    float4 acc[4];
    #pragma unroll
    for (int i = 0; i < 4; ++i) acc[i] = make_float4(0.f, 0.f, 0.f, 0.f);
    for (int kc = 0; kc < 4; ++kc) {
        const float* mp = mid + ((size_t)(m0 + r)) * 256 + kc * 64 + cpart;
        float4 av[4];
        #pragma unroll
        for (int i = 0; i < 4; ++i) av[i] = *(const float4*)(mp + i * 4);
        const float* wp = W2 + (size_t)(kc * 64 + r) * 64 + cpart;
        float4 wv4[4];
        #pragma unroll
        for (int i = 0; i < 4; ++i) wv4[i] = *(const float4*)(wp + i * 4);
        __syncthreads();
        #pragma unroll
        for (int i = 0; i < 4; ++i) {
            *(float4*)&As[r * 68 + cpart + i * 4] = av[i];
            *(float4*)&Bs[r * 64 + cpart + i * 4] = wv4[i];
        }
        __syncthreads();
        #pragma unroll 4
        for (int k4 = 0; k4 < 16; ++k4) {
            float4 a[4], b[4];
            #pragma unroll
            for (int i = 0; i < 4; ++i) a[i] = *(float4*)&As[(ty + 16 * i) * 68 + k4 * 4];
            #pragma unroll
            for (int kk = 0; kk < 4; ++kk) b[kk] = *(float4*)&Bs[(k4 * 4 + kk) * 64 + tx * 4];
            #pragma unroll
            for (int i = 0; i < 4; ++i) {
                fma4(acc[i], a[i].x, b[0]);
                fma4(acc[i], a[i].y, b[1]);
                fma4(acc[i], a[i].z, b[2]);
                fma4(acc[i], a[i].w, b[3]);
            }
        }
    }
    int col = tx * 4;
    float4 b2v = *(const float4*)(b2 + col);
    #pragma unroll
    for (int i = 0; i < 4; ++i) {
        int row = m0 + ty + 16 * i;
        float4 hv = *(const float4*)(hbuf + (size_t)row * 64 + col);
        float4 ov;
        ov.x = acc[i].x + b2v.x + hv.x;
        ov.y = acc[i].y + b2v.y + hv.y;
        ov.z = acc[i].z + b2v.z + hv.z;
        ov.w = acc[i].w + b2v.w + hv.w;
        *(float4*)&out[(size_t)row * 64 + col] = ov;
    }
}

// ---------- bottleneck ----------
__global__ __launch_bounds__(256) void k_bneck(
    const float* __restrict__ xenc, const float* __restrict__ m1W, const float* __restrict__ m1b,
    const float* __restrict__ m4W, const float* __restrict__ m4b,
    float* __restrict__ lat_out, float* __restrict__ xdec)
{
    int tid = threadIdx.x, w = tid >> 6, l = tid & 63;
    int row = blockIdx.x * 4 + w;
    if (row >= 128 * 196) return;
    int n = row / 196, p = row - n * 196;
    float xv = xenc[((size_t)(n * 197 + 1 + p)) * 64 + l];
    float sum = wave_sum(xv * m1W[l]);
    float lat = gelu_f(sum + m1b[0]);
    if (l == 0) lat_out[row] = lat;
    float ov = gelu_f(lat * m4W[l] + m4b[l]);
    xdec[(size_t)row * 64 + l] = ov;
}

// ---------- final: img = depatchify((x + pe196) @ lm2_W + lm2_b) ----------
// grid rows/64; A staged once; loop 16 column tiles with LDS-staged B.
__global__ __launch_bounds__(256, 2) void k_final(
    const float* __restrict__ xdec, const float* __restrict__ pe,
    const float* __restrict__ W, const float* __restrict__ bias,
    float* __restrict__ img_out)
{
    __shared__ float As[64 * 68];
    __shared__ float Bs[64 * 64];
    int tid = threadIdx.x;
    int tx = tid & 15, ty = tid >> 4;
    int m0 = blockIdx.x * 64;
    int r = tid >> 2, cpart = (tid & 3) * 16;
    {
        int row = m0 + r;
        int n = row / 196, p = row - n * 196;
        const float* xp = xdec + (size_t)row * 64 + cpart;
        const float* pp = pe + (size_t)p * 64 + cpart;
        #pragma unroll
        for (int i = 0; i < 4; ++i) {
            float4 xv = *(const float4*)(xp + i * 4);
            float4 pv = *(const float4*)(pp + i * 4);
            float4 zv;
            zv.x = xv.x + pv.x; zv.y = xv.y + pv.y; zv.z = xv.z + pv.z; zv.w = xv.w + pv.w;
            *(float4*)&As[r * 68 + cpart + i * 4] = zv;
        }
    }
    for (int nb = 0; nb < 16; ++nb) {
        const float* wp = W + (size_t)r * 1024 + nb * 64 + cpart;
        float4 wv4[4];
        #pragma unroll
        for (int i = 0; i < 4; ++i) wv4[i] = *(const float4*)(wp + i * 4);
        __syncthreads();
        #pragma unroll
        for (int i = 0; i < 4; ++i)
            *(float4*)&Bs[r * 64 + cpart + i * 4] = wv4[i];
        __syncthreads();
        float4 acc[4];
        #pragma unroll
        for (int i = 0; i < 4; ++i) acc[i] = make_float4(0.f, 0.f, 0.f, 0.f);
        #pragma unroll 4
        for (int k4 = 0; k4 < 16; ++k4) {
            float4 a[4], b[4];
            #pragma unroll
            for (int i = 0; i < 4; ++i) a[i] = *(float4*)&As[(ty + 16 * i) * 68 + k4 * 4];
            #pragma unroll
            for (int kk = 0; kk < 4; ++kk) b[kk] = *(float4*)&Bs[(k4 * 4 + kk) * 64 + tx * 4];
            #pragma unroll
            for (int i = 0; i < 4; ++i) {
                fma4(acc[i], a[i].x, b[0]);
                fma4(acc[i], a[i].y, b[1]);
                fma4(acc[i], a[i].z, b[2]);
                fma4(acc[i], a[i].w, b[3]);
            }
        }
        int colj = nb * 64 + tx * 4;
        float4 bv = *(const float4*)(bias + colj);
        int rr = colj >> 5, cc = colj & 31;
        #pragma unroll
        for (int i = 0; i < 4; ++i) {
            int row = m0 + ty + 16 * i;
            int n = row / 196, p = row - n * 196;
            int pi = p / 14, pj = p - pi * 14;
            size_t off = (size_t)n * 200704 + (size_t)(pi * 32 + rr) * 448 + pj * 32 + cc;
            float4 ov;
            ov.x = acc[i].x + bv.x;
            ov.y = acc[i].y + bv.y;
            ov.z = acc[i].z + bv.z;
            ov.w = acc[i].w + bv.w;
            *(float4*)&img_out[off] = ov;
        }
    }
}

// ---------- host launch ----------
extern "C" void kernel_launch(void* const* d_in, const int* in_sizes, int n_in,
                              void* d_out, int out_size, void* d_ws, size_t ws_size,
                              hipStream_t stream) {
    const float* images = (const float*)d_in[0];
    const float* cls    = (const float*)d_in[1];
    const float* lm_W   = (const float*)d_in[2];
    const float* lm_b   = (const float*)d_in[3];
    const float* lm2_W  = (const float*)d_in[4];
    const float* lm2_b  = (const float*)d_in[5];
    const float* m1W    = (const float*)d_in[6];
    const float* m1b    = (const float*)d_in[7];
    const float* m4W    = (const float*)d_in[8];
    const float* m4b    = (const float*)d_in[9];

    float* pe   = (float*)d_ws;
    float* xb   = pe + 12608;          // 128*197*64
    float* hb   = xb + 1614848;
    float* qb   = hb + 1614848;
    float* kb   = qb + 1614848;
    float* vb   = kb + 1614848;
    float* midb = vb + 1614848;        // 25216*256

    float* lat_out = (float*)d_out;            // 128*196 floats
    float* img_out = (float*)d_out + 25088;    // 128*448*448 floats

    hipLaunchKernelGGL(k_posemb, dim3(50), dim3(256), 0, stream, pe);
    hipLaunchKernelGGL(k_patch, dim3(392), dim3(256), 0, stream, images, lm_W, lm_b, pe, xb);
    hipLaunchKernelGGL(k_cls, dim3(32), dim3(256), 0, stream, cls, pe, xb);

    float* cur_x = xb;
    float* cur_h = hb;
    for (int grp = 0; grp < 2; ++grp) {
        int base = 10 + grp * 14;
        const float* ln1_g = (const float*)d_in[base + 0];
        const float* ln1_b = (const float*)d_in[base + 1];
        const float* ln2_g = (const float*)d_in[base + 2];
        const float* ln2_b = (const float*)d_in[base + 3];
        const float* Wq = (const float*)d_in[base + 4];
        const float* Wk = (const float*)d_in[base + 5];
        const float* Wv = (const float*)d_in[base + 6];
        const float* bq = (const float*)d_in[base + 7];
        const float* bk = (const float*)d_in[base + 8];
        const float* bv = (const float*)d_in[base + 9];
        const float* W1 = (const float*)d_in[base + 10];
        const float* b1 = (const float*)d_in[base + 11];
        const float* W2 = (const float*)d_in[base + 12];
        const float* b2 = (const float*)d_in[base + 13];
        int S = (grp == 0) ? 197 : 196;
        int rows = 128 * S;
        for (int i = 0; i < 2; ++i) {
            hipLaunchKernelGGL(k_ln_qkv, dim3(rows / 4), dim3(256), 0, stream,
                cur_x, ln1_g + i * 64, ln1_b + i * 64,
                Wq + i * 1024, bq + i * 64, Wk + i * 1024, bk + i * 64,
                Wv + i * 1024, bv + i * 64, qb, kb, vb, S);
            hipLaunchKernelGGL(k_attn, dim3(512), dim3(256), 0, stream,
                qb, kb, vb, cur_x, cur_h, S);
            hipLaunchKernelGGL(k_mlp1, dim3(rows / 64), dim3(256), 0, stream,
                cur_h, ln2_g + i * 64, ln2_b + i * 64, W1 + i * 16384, b1 + i * 256, midb);
            hipLaunchKernelGGL(k_mlp2, dim3(rows / 64), dim3(256), 0, stream,
                midb, W2 + i * 16384, b2 + i * 64, cur_h, cur_x);
        }
        if (grp == 0) {
            hipLaunchKernelGGL(k_bneck, dim3(6272), dim3(256), 0, stream,
                cur_x, m1W, m1b, m4W, m4b, lat_out, hb);
            cur_x = hb;
            cur_h = xb;
        }
    }
    hipLaunchKernelGGL(k_final, dim3(392), dim3(256), 0, stream, cur_x, pe, lm2_W, lm2_b, img_out);
}